// Round 7
// baseline (36.271 us; speedup 1.0000x reference)
//
#include <hip/hip_runtime.h>

// RecModel — round 7: software-pipelined gather⇄compute.
// Block = 256 thr = 4 waves owns TWO 16-row tiles; T1's gather loads are
// issued into registers BEFORE compute_tile(T0), consumed after (T14 pattern).
// Numerics identical to round 5 (emb hi-only bf16, bf16 W0 history, hi/lo A2).

using u16 = unsigned short;
typedef __attribute__((ext_vector_type(8))) short short8v;
typedef __attribute__((ext_vector_type(4))) short short4v;
typedef __attribute__((ext_vector_type(4))) float floatx4;

constexpr int W1_ELEMS = 13 * 8 * 64 * 8;  // 53248
constexpr int W2_ELEMS = 5 * 7 * 64 * 8;   // 17920
constexpr int W0_ELEMS = 100001 * 16;      // 1600016

__device__ __forceinline__ u16 f2bf(float f) {
  unsigned u = __float_as_uint(f);
  unsigned r = (u + 0x7fffu + ((u >> 16) & 1u)) >> 16;  // RN-even
  return (u16)r;
}
__device__ __forceinline__ float bf2f(u16 h) {
  return __uint_as_float(((unsigned)h) << 16);
}

// ---- precompute: weight frags + W0 -> bf16 (same as round 5) ----
__global__ void precompute(const float* __restrict__ w1, const float* __restrict__ w2,
                           const float* __restrict__ W,
                           u16* __restrict__ w1h, u16* __restrict__ w2h,
                           u16* __restrict__ w0b) {
  int b = blockIdx.x;
  if (b < 35) {
    int tid = b * 256 + threadIdx.x;
    if (tid < 13 * 8 * 64) {
      int l = tid & 63;
      int g = tid >> 6;
      int kt = g & 7, nt = g >> 3;
      int n = nt * 16 + (l & 15);
      int kb = kt * 32 + (l >> 4) * 8;
      short8v h8;
#pragma unroll
      for (int e = 0; e < 8; ++e) {
        int k = kb + e;
        float v = (n < 200 && k < 241) ? w1[n * 241 + k] : 0.f;
        h8[e] = (short)f2bf(v);
      }
      *(short8v*)&w1h[tid * 8] = h8;
    } else if (tid < 13 * 8 * 64 + 5 * 7 * 64) {
      int t2 = tid - 13 * 8 * 64;
      int l = t2 & 63;
      int g = t2 >> 6;
      int kt = g % 7, nt = g / 7;
      int n = nt * 16 + (l & 15);
      int kb = kt * 32 + (l >> 4) * 8;
      short8v h8;
#pragma unroll
      for (int e = 0; e < 8; ++e) {
        int k = kb + e;
        float v = (k < 200) ? w2[n * 200 + k] : 0.f;
        h8[e] = (short)f2bf(v);
      }
      *(short8v*)&w2h[t2 * 8] = h8;
    }
  } else {
    int t = (b - 35) * 256 + threadIdx.x;
    int base = t * 8;
    if (base < W0_ELEMS) {
      floatx4 f0 = *(const floatx4*)(W + base);
      floatx4 f1 = *(const floatx4*)(W + base + 4);
      short8v o;
      o[0] = (short)f2bf(f0[0]);
      o[1] = (short)f2bf(f0[1]);
      o[2] = (short)f2bf(f0[2]);
      o[3] = (short)f2bf(f0[3]);
      o[4] = (short)f2bf(f1[0]);
      o[5] = (short)f2bf(f1[1]);
      o[6] = (short)f2bf(f1[2]);
      o[7] = (short)f2bf(f1[3]);
      *(short8v*)(w0b + base) = o;
    }
  }
}

struct GatherRegs {
  floatx4 ev[4];  // embedding quads
  short8v hv[7];  // history bf16 rows
  float dv;       // dense
};

__device__ __forceinline__ void gather_issue(const int* __restrict__ sf,
                                             const int* __restrict__ hist,
                                             const float* __restrict__ dense,
                                             const float* __restrict__ W,
                                             const u16* __restrict__ w0b,
                                             int row0, int tid, GatherRegs& gr) {
  // embeddings: it=0..2 unconditional, it=3 for tid<128
#pragma unroll
  for (int it = 0; it < 4; ++it) {
    int g = tid + it * 256;
    if (g < 896) {
      int q = g & 3, rt = g >> 2, r = rt & 15, t = rt >> 4;
      int idx = sf[(row0 + r) * 14 + t] + 1;  // [1,100000]
      gr.ev[it] = *(const floatx4*)(W + ((size_t)t * 100001 + (size_t)idx) * 16 + q * 4);
    }
  }
  // history: 16 thr/row = q(2 halves) x s(8-way split)
  int r = tid >> 4, rem = tid & 15, q = rem & 1, s = rem >> 1;
  const int* hp = hist + (row0 + r) * 50;
  const u16* Wq = w0b + q * 8;
#pragma unroll
  for (int hh = 0; hh < 6; ++hh) {
    int idx = hp[s + hh * 8] + 1;
    gr.hv[hh] = *(const short8v*)(Wq + (size_t)idx * 16);
  }
  if (s < 2) {
    int idx = hp[48 + s] + 1;
    gr.hv[6] = *(const short8v*)(Wq + (size_t)idx * 16);
  }
  gr.dv = dense[row0 + r];
}

__device__ __forceinline__ void gather_finish(int tid, const GatherRegs& gr,
                                              u16* A1hb, u16* A1l7b) {
  short8v z8 = {0, 0, 0, 0, 0, 0, 0, 0};
  // embeddings -> A1h (hi only), kt 0..6
#pragma unroll
  for (int it = 0; it < 4; ++it) {
    int g = tid + it * 256;
    if (g < 896) {
      int q = g & 3, rt = g >> 2, r = rt & 15, t = rt >> 4;
      int k0 = t * 16 + q * 4, kt = k0 >> 5, kg = (k0 >> 3) & 3, e0 = k0 & 7;
      short4v h4;
#pragma unroll
      for (int d = 0; d < 4; ++d) h4[d] = (short)f2bf(gr.ev[it][d]);
      *(short4v*)&A1hb[(kt * 64 + kg * 16 + r) * 8 + e0] = h4;
    }
  }
  // history: sum + shfl combine -> kt=7 slab (hi/lo)
  int r = tid >> 4, rem = tid & 15, q = rem & 1, s = rem >> 1;
  float a[8] = {0.f, 0.f, 0.f, 0.f, 0.f, 0.f, 0.f, 0.f};
#pragma unroll
  for (int hh = 0; hh < 6; ++hh)
#pragma unroll
    for (int d = 0; d < 8; ++d) a[d] += bf2f((u16)gr.hv[hh][d]);
  if (s < 2)
#pragma unroll
    for (int d = 0; d < 8; ++d) a[d] += bf2f((u16)gr.hv[6][d]);
#pragma unroll
  for (int d = 0; d < 8; ++d) {
    a[d] += __shfl_xor(a[d], 2);
    a[d] += __shfl_xor(a[d], 4);
    a[d] += __shfl_xor(a[d], 8);
  }
  if (s == 0) {
    short8v h8, l8;
#pragma unroll
    for (int d = 0; d < 8; ++d) {
      u16 hi = f2bf(a[d]);
      h8[d] = (short)hi;
      l8[d] = (short)f2bf(a[d] - bf2f(hi));
    }
    *(short8v*)&A1hb[(7 * 64 + q * 16 + r) * 8] = h8;
    *(short8v*)&A1l7b[(q * 16 + r) * 8] = l8;
    if (q == 0) {
      u16 dh = f2bf(gr.dv), dl = f2bf(gr.dv - bf2f(dh));
      short8v dh8 = z8, dl8 = z8;
      dh8[0] = (short)dh;
      dl8[0] = (short)dl;
      *(short8v*)&A1hb[(7 * 64 + 32 + r) * 8] = dh8;
      *(short8v*)&A1l7b[(32 + r) * 8] = dl8;
      *(short8v*)&A1hb[(7 * 64 + 48 + r) * 8] = z8;
      *(short8v*)&A1l7b[(48 + r) * 8] = z8;
    }
  }
}

__device__ __forceinline__ void compute_tile(
    const u16* A1hb, const u16* A1l7b, u16* A2h, u16* A2l, float* o2,
    int row0, int tid, const u16* __restrict__ w1h, const u16* __restrict__ w2h,
    const float* __restrict__ b1, const float* __restrict__ b2,
    const float* __restrict__ w3, const float* __restrict__ b3,
    float* __restrict__ out) {
  const int l = tid & 63;
  const int wv = tid >> 6;
  short8v z8 = {0, 0, 0, 0, 0, 0, 0, 0};
  const int ntbase = (wv == 0) ? 0 : 4 + 3 * (wv - 1);
  const int ntcnt = (wv == 0) ? 4 : 3;

  // GEMM1 B prefetch (kt 0,1)
  short8v bhr[2][4];
#pragma unroll
  for (int kk = 0; kk < 2; ++kk)
#pragma unroll
    for (int i = 0; i < 4; ++i)
      bhr[kk][i] = (i < ntcnt) ? *(const short8v*)&w1h[(((ntbase + i) * 8 + kk) * 64 + l) * 8]
                               : z8;

  // ---- GEMM1: hi all 8 kt, lo only kt=7 ----
  floatx4 acc[4];
#pragma unroll
  for (int i = 0; i < 4; ++i) acc[i] = (floatx4){0.f, 0.f, 0.f, 0.f};

#pragma unroll
  for (int kt = 0; kt < 8; ++kt) {
    short8v ah = *(const short8v*)&A1hb[(kt * 64 + l) * 8];
    short8v al7;
    if (kt == 7) al7 = *(const short8v*)&A1l7b[l * 8];
#pragma unroll
    for (int i = 0; i < 4; ++i) {
      if (i < ntcnt) {
        short8v cb = bhr[kt & 1][i];
        if (kt < 6) bhr[kt & 1][i] = *(const short8v*)&w1h[(((ntbase + i) * 8 + kt + 2) * 64 + l) * 8];
        acc[i] = __builtin_amdgcn_mfma_f32_16x16x32_bf16(ah, cb, acc[i], 0, 0, 0);
        if (kt == 7) acc[i] = __builtin_amdgcn_mfma_f32_16x16x32_bf16(al7, cb, acc[i], 0, 0, 0);
      }
    }
  }

  // GEMM2 B prefetch (kt2 = 0,1)
  const int ntA = wv;  // wave0 also handles nt2=4
  short8v bra[2], brb[2];
  bra[0] = *(const short8v*)&w2h[((ntA * 7 + 0) * 64 + l) * 8];
  bra[1] = *(const short8v*)&w2h[((ntA * 7 + 1) * 64 + l) * 8];
  if (wv == 0) {
    brb[0] = *(const short8v*)&w2h[((4 * 7 + 0) * 64 + l) * 8];
    brb[1] = *(const short8v*)&w2h[((4 * 7 + 1) * 64 + l) * 8];
  } else {
    brb[0] = z8;
    brb[1] = z8;
  }

  // ---- epilogue1: bias+relu -> A2 (hi/lo) ----
#pragma unroll
  for (int i = 0; i < 4; ++i) {
    if (i < ntcnt) {
      int n = (ntbase + i) * 16 + (l & 15);
      float bias = (n < 200) ? b1[n] : 0.f;
#pragma unroll
      for (int g = 0; g < 4; ++g) {
        float v = (n < 200) ? fmaxf(acc[i][g] + bias, 0.f) : 0.f;
        int m = (l >> 4) * 4 + g;
        u16 hi = f2bf(v), lo = f2bf(v - bf2f(hi));
        int kt2 = n >> 5, kg2 = (n >> 3) & 3, e = n & 7;
        int pos = (kt2 * 64 + kg2 * 16 + m) * 8 + e;
        A2h[pos] = hi;
        A2l[pos] = lo;
      }
    }
  }
  if (wv == 1 && l < 32) {  // zero k2 in [208,224)
    *(short8v*)&A2h[(6 * 64 + 32 + l) * 8] = z8;
    *(short8v*)&A2l[(6 * 64 + 32 + l) * 8] = z8;
  }
  __syncthreads();  // A2 complete

  // ---- GEMM2 ----
  floatx4 acca = (floatx4){0.f, 0.f, 0.f, 0.f};
  floatx4 accb = (floatx4){0.f, 0.f, 0.f, 0.f};
#pragma unroll
  for (int kt = 0; kt < 7; ++kt) {
    short8v ah = *(const short8v*)&A2h[(kt * 64 + l) * 8];
    short8v al = *(const short8v*)&A2l[(kt * 64 + l) * 8];
    short8v ca = bra[kt & 1];
    if (kt < 5) bra[kt & 1] = *(const short8v*)&w2h[((ntA * 7 + kt + 2) * 64 + l) * 8];
    acca = __builtin_amdgcn_mfma_f32_16x16x32_bf16(ah, ca, acca, 0, 0, 0);
    acca = __builtin_amdgcn_mfma_f32_16x16x32_bf16(al, ca, acca, 0, 0, 0);
    if (wv == 0) {
      short8v cb = brb[kt & 1];
      if (kt < 5) brb[kt & 1] = *(const short8v*)&w2h[((4 * 7 + kt + 2) * 64 + l) * 8];
      accb = __builtin_amdgcn_mfma_f32_16x16x32_bf16(ah, cb, accb, 0, 0, 0);
      accb = __builtin_amdgcn_mfma_f32_16x16x32_bf16(al, cb, accb, 0, 0, 0);
    }
  }

  // ---- epilogue2 -> o2 [16][84] ----
  {
    int n = ntA * 16 + (l & 15);
    float bias = b2[n];
#pragma unroll
    for (int g = 0; g < 4; ++g) {
      int r = (l >> 4) * 4 + g;
      o2[r * 84 + n] = fmaxf(acca[g] + bias, 0.f);
    }
    if (wv == 0) {
      int n2 = 64 + (l & 15);
      float bias2 = b2[n2];
#pragma unroll
      for (int g = 0; g < 4; ++g) {
        int r = (l >> 4) * 4 + g;
        o2[r * 84 + n2] = fmaxf(accb[g] + bias2, 0.f);
      }
    }
  }
  __syncthreads();  // o2 complete

  // ---- fc3 ----
  if (tid < 32) {
    int r = tid >> 1, o = tid & 1;
    float a = b3[o];
    const float* orow = &o2[r * 84];
    const float* wrow = &w3[o * 80];
#pragma unroll
    for (int j = 0; j < 80; j += 4) {
      floatx4 xv = *(const floatx4*)&orow[j];
      floatx4 wv4 = *(const floatx4*)&wrow[j];
      a += xv[0] * wv4[0] + xv[1] * wv4[1] + xv[2] * wv4[2] + xv[3] * wv4[3];
    }
    out[(row0 + r) * 2 + o] = a;
  }
}

// ---- main kernel: 512 blocks x 256 thr, 2 tiles/block, pipelined ----
__global__ __launch_bounds__(256, 2) void mlp_kernel(
    const int* __restrict__ sf, const float* __restrict__ dense,
    const int* __restrict__ hist, const float* __restrict__ W,
    const u16* __restrict__ w0b, const u16* __restrict__ w1h,
    const u16* __restrict__ w2h, const float* __restrict__ b1,
    const float* __restrict__ b2, const float* __restrict__ w3,
    const float* __restrict__ b3, float* __restrict__ out) {
  __shared__ u16 A1h[2][8 * 64 * 8];  // 16KB (double-buffered)
  __shared__ u16 A1l7[2][64 * 8];     // 2KB
  __shared__ u16 A2h[7 * 64 * 8], A2l[7 * 64 * 8];  // 14KB (single)
  __shared__ float o2[16 * 84];                     // 5.25KB

  const int tid = threadIdx.x;
  const int row0 = blockIdx.x * 32;  // tiles: [row0, row0+16)

  // T0 gather (exposed)
  GatherRegs gr0;
  gather_issue(sf, hist, dense, W, w0b, row0, tid, gr0);
  gather_finish(tid, gr0, A1h[0], A1l7[0]);
  __syncthreads();  // A1[0] ready

  // T1 gather ISSUE — latency hides under compute_tile(T0)
  GatherRegs gr1;
  gather_issue(sf, hist, dense, W, w0b, row0 + 16, tid, gr1);

  compute_tile(A1h[0], A1l7[0], A2h, A2l, o2, row0, tid,
               w1h, w2h, b1, b2, w3, b3, out);

  gather_finish(tid, gr1, A1h[1], A1l7[1]);
  __syncthreads();  // A1[1] ready; also fences T0's A2/o2 readers vs T1 writers

  compute_tile(A1h[1], A1l7[1], A2h, A2l, o2, row0 + 16, tid,
               w1h, w2h, b1, b2, w3, b3, out);
}

extern "C" void kernel_launch(void* const* d_in, const int* in_sizes, int n_in,
                              void* d_out, int out_size, void* d_ws, size_t ws_size,
                              hipStream_t stream) {
  const int* sf = (const int*)d_in[0];
  const float* dense = (const float*)d_in[1];
  const int* hist = (const int*)d_in[2];
  const float* W = (const float*)d_in[3];
  const float* w1 = (const float*)d_in[4];
  const float* b1 = (const float*)d_in[5];
  const float* w2 = (const float*)d_in[6];
  const float* b2 = (const float*)d_in[7];
  const float* w3 = (const float*)d_in[8];
  const float* b3 = (const float*)d_in[9];
  float* out = (float*)d_out;

  u16* w1h = (u16*)d_ws;
  u16* w2h = w1h + W1_ELEMS;
  u16* w0b = w2h + W2_ELEMS;

  int conv_blocks = (W0_ELEMS / 8 + 255) / 256;  // 782
  precompute<<<dim3(35 + conv_blocks), dim3(256), 0, stream>>>(w1, w2, W, w1h, w2h, w0b);
  mlp_kernel<<<dim3(512), dim3(256), 0, stream>>>(sf, dense, hist, W, w0b, w1h, w2h,
                                                  b1, b2, w3, b3, out);
}